// Round 11
// baseline (144.862 us; speedup 1.0000x reference)
//
#include <hip/hip_runtime.h>

#define Bn 2
#define Ln 2048
#define DIN 256
#define Hn 8
#define DEPTH 32
#define SCALE 0.17677669529663687f      // 1/sqrt(32)
#define NEGC (-4294967296.0f)           // float32(-2^32+1)

typedef _Float16 f16;
typedef _Float16 h8 __attribute__((ext_vector_type(8)));   // K=32 A/B frag: 4 VGPR
typedef _Float16 h4 __attribute__((ext_vector_type(4)));   // K=16 A/B frag: 2 VGPR
typedef float f4 __attribute__((ext_vector_type(4)));      // C/D frag: 4 f32

#define WLS 264   // LDS W^T row stride (f16): 528B, 16B-aligned frags

// ===========================================================================
// MFMA pipeline. Fragment layouts (verified m89/m91/m120):
//   K=32: A[m=lane&15][k=quad*8+j]  B[n=lane&15][k=quad*8+j]
//   K=16: A[m=lane&15][k=quad*4+j]  B[n=lane&15][k=quad*4+j]
//   D[row m = quad*4+reg][col n = lane&15]   (both shapes)
// flash: S^T = K.Q^T (K=32) with mask bias in C-init; exp'd S^T C-regs are
// *directly* the K=16 PV B-frags (layout identity) -> no LDS in main loop.
// ===========================================================================

// ---- Kernel 1: QKV projection GEMM. Block: 128m x 64n, W^T staged in LDS
// once per block (f16). Wave = 32 m-rows (2 m-frags): 64 MFMA/wave.
// Q (pre-scaled) / K head-major [b,h,L,32]; V TRANSPOSED [b,h,32,L].
__global__ __launch_bounds__(256) void proj_gemm(
    const float* __restrict__ Xq, const float* __restrict__ Xk, const float* __restrict__ Xv,
    const float* __restrict__ Wq, const float* __restrict__ Wk, const float* __restrict__ Wv,
    const float* __restrict__ bq, const float* __restrict__ bk, const float* __restrict__ bv,
    f16* __restrict__ Qb, f16* __restrict__ Kb, f16* __restrict__ Vt)
{
    __shared__ f16 Wl[64 * WLS];   // 33 KB: W^T tile [n_local][k]
    const int p = blockIdx.z;
    const float* X = p == 0 ? Xq : p == 1 ? Xk : Xv;
    const float* W = p == 0 ? Wq : p == 1 ? Wk : Wv;
    const float* bias = p == 0 ? bq : p == 1 ? bk : bv;

    const int t = threadIdx.x, w = t >> 6, lane = t & 63;
    const int l15 = lane & 15, quad = lane >> 4;
    const int n0 = blockIdx.y * 64;

    {   // stage W[k][n0+nl] -> Wl[nl][k] (f16); coalesced 256B global rows
        const int nl = t & 63, kb = t >> 6;
        for (int kk = 0; kk < 64; ++kk) {
            const int k = kk * 4 + kb;
            Wl[nl * WLS + k] = (f16)W[(size_t)k * DIN + n0 + nl];
        }
    }
    __syncthreads();

    const int m0w = blockIdx.x * 128 + w * 32;
    const float* A0 = X + (size_t)(m0w + l15) * DIN;
    const float* A1 = X + (size_t)(m0w + 16 + l15) * DIN;

    f4 acc[2][4];
    #pragma unroll
    for (int mi = 0; mi < 2; ++mi)
        #pragma unroll
        for (int tt = 0; tt < 4; ++tt) acc[mi][tt] = (f4){0.f, 0.f, 0.f, 0.f};

    for (int k0 = 0; k0 < DIN; k0 += 32) {
        float4 xa0 = *(const float4*)(A0 + k0 + quad * 8);
        float4 xb0 = *(const float4*)(A0 + k0 + quad * 8 + 4);
        float4 xa1 = *(const float4*)(A1 + k0 + quad * 8);
        float4 xb1 = *(const float4*)(A1 + k0 + quad * 8 + 4);
        h8 af0 = { (f16)xa0.x, (f16)xa0.y, (f16)xa0.z, (f16)xa0.w,
                   (f16)xb0.x, (f16)xb0.y, (f16)xb0.z, (f16)xb0.w };
        h8 af1 = { (f16)xa1.x, (f16)xa1.y, (f16)xa1.z, (f16)xa1.w,
                   (f16)xb1.x, (f16)xb1.y, (f16)xb1.z, (f16)xb1.w };
        #pragma unroll
        for (int tt = 0; tt < 4; ++tt) {
            h8 bf = *(const h8*)(Wl + (tt * 16 + l15) * WLS + k0 + quad * 8);
            acc[0][tt] = __builtin_amdgcn_mfma_f32_16x16x32_f16(af0, bf, acc[0][tt], 0, 0, 0);
            acc[1][tt] = __builtin_amdgcn_mfma_f32_16x16x32_f16(af1, bf, acc[1][tt], 0, 0, 0);
        }
    }
    #pragma unroll
    for (int mi = 0; mi < 2; ++mi)
        #pragma unroll
        for (int tt = 0; tt < 4; ++tt) {
            const int c = n0 + tt * 16 + l15;        // 16-tile never straddles a head
            const float bb = bias[c];
            const int h = c >> 5, dd = c & 31;
            #pragma unroll
            for (int r = 0; r < 4; ++r) {
                const int row = m0w + mi * 16 + quad * 4 + r;
                const int b = row >> 11, l = row & (Ln - 1);
                const float v = acc[mi][tt][r] + bb;
                if (p == 0)
                    Qb[(((size_t)(b * Hn + h)) * Ln + l) * DEPTH + dd] = (f16)(v * SCALE);
                else if (p == 1)
                    Kb[(((size_t)(b * Hn + h)) * Ln + l) * DEPTH + dd] = (f16)v;
                else
                    Vt[(((size_t)(b * Hn + h)) * DEPTH + dd) * Ln + l] = (f16)v;
            }
        }
}

// ---- Kernel 2: split-K MFMA flash, LDS-free main loop. --------------------
// Grid (hb=16, 64): block = 32 q-rows; wave w = keys [w*512,(w+1)*512).
// Per 64-key tile: 8 S-MFMA (K=32) + 16 PV-MFMA (K=16, B-frag = exp'd S^T).
__global__ __launch_bounds__(256) void flash_mfma(
    const f16* __restrict__ Qb, const f16* __restrict__ Kb,
    const f16* __restrict__ Vt, const int* __restrict__ mask,
    f16* __restrict__ Ob)
{
    __shared__ float Os[4][32][34];    // 17408 B, partial O^T [w][d][q]
    __shared__ float lS[4][32];
    const int t = threadIdx.x, w = t >> 6, lane = t & 63;
    const int l15 = lane & 15, quad = lane >> 4;
    const int hb = blockIdx.x;                 // h = hb&7, b = hb>>3; lid%8=hb%8 (XCD)
    const int q0 = blockIdx.y * 32;
    const int b = hb >> 3;
    const f16* Qh = Qb + (size_t)hb * Ln * DEPTH;
    const f16* Kh = Kb + (size_t)hb * Ln * DEPTH;
    const f16* Vh = Vt + (size_t)hb * DEPTH * Ln;
    const int* mrow = mask + b * Ln;
    const int k_base = w * (Ln / 4);

    const h8 qf0 = *(const h8*)(Qh + (size_t)(q0 + l15) * DEPTH + quad * 8);      // B-frags
    const h8 qf1 = *(const h8*)(Qh + (size_t)(q0 + 16 + l15) * DEPTH + quad * 8);

    f4 o[2][2];                                 // [d-group][q-group]
    #pragma unroll
    for (int i = 0; i < 2; ++i)
        #pragma unroll
        for (int j = 0; j < 2; ++j) o[i][j] = (f4){0.f, 0.f, 0.f, 0.f};
    float l_run[2] = {0.f, 0.f};                // per-lane q = q0 + qg*16 + l15

    for (int kt = 0; kt < Ln / 4 / 64; ++kt) {
        const int k0 = k_base + kt * 64;
        // ---- S^T = K.Q^T + maskbias; V A-frags prefetched alongside ----
        f4 s[4][2];
        h4 va[4][2];
        #pragma unroll
        for (int tt = 0; tt < 4; ++tt) {
            h8 kf = *(const h8*)(Kh + (size_t)(k0 + tt * 16 + l15) * DEPTH + quad * 8);
            const int4 mk = *(const int4*)(mrow + k0 + tt * 16 + quad * 4);
            f4 bias4 = { mk.x ? 0.f : NEGC, mk.y ? 0.f : NEGC,
                         mk.z ? 0.f : NEGC, mk.w ? 0.f : NEGC };
            s[tt][0] = __builtin_amdgcn_mfma_f32_16x16x32_f16(kf, qf0, bias4, 0, 0, 0);
            s[tt][1] = __builtin_amdgcn_mfma_f32_16x16x32_f16(kf, qf1, bias4, 0, 0, 0);
            va[tt][0] = *(const h4*)(Vh + (size_t)l15 * Ln        + k0 + tt * 16 + quad * 4);
            va[tt][1] = *(const h4*)(Vh + (size_t)(16 + l15) * Ln + k0 + tt * 16 + quad * 4);
        }
        // ---- P = exp(S^T) in-register: C-regs ARE the K=16 PV B-frags ----
        #pragma unroll
        for (int tt = 0; tt < 4; ++tt)
            #pragma unroll
            for (int qg = 0; qg < 2; ++qg) {
                h4 pf;
                #pragma unroll
                for (int r = 0; r < 4; ++r) {
                    const float pv = __expf(s[tt][qg][r]);
                    l_run[qg] += pv;
                    pf[r] = (f16)pv;
                }
                o[0][qg] = __builtin_amdgcn_mfma_f32_16x16x16f16(va[tt][0], pf, o[0][qg], 0, 0, 0);
                o[1][qg] = __builtin_amdgcn_mfma_f32_16x16x16f16(va[tt][1], pf, o[1][qg], 0, 0, 0);
            }
    }
    // ---- wave partials ----
    #pragma unroll
    for (int qg = 0; qg < 2; ++qg) {
        l_run[qg] += __shfl_xor(l_run[qg], 16, 64);
        l_run[qg] += __shfl_xor(l_run[qg], 32, 64);
        if (quad == 0) lS[w][qg * 16 + l15] = l_run[qg];
        #pragma unroll
        for (int dg = 0; dg < 2; ++dg)
            #pragma unroll
            for (int r = 0; r < 4; ++r)
                Os[w][dg * 16 + quad * 4 + r][qg * 16 + l15] = o[dg][qg][r];
    }
    __syncthreads();

    // ---- combine 4 chunks: thread -> (q = t&31, d = (t>>5) + 8i) ----
    {
        const int cq = t & 31, d0 = t >> 5;
        const float ls = lS[0][cq] + lS[1][cq] + lS[2][cq] + lS[3][cq];
        const float inv = 1.0f / ls;
        f16* Oq = Ob + ((size_t)hb * Ln + q0 + cq) * DEPTH;
        #pragma unroll
        for (int i = 0; i < 4; ++i) {
            const int dd = d0 + 8 * i;
            const float ov = Os[0][dd][cq] + Os[1][dd][cq] +
                             Os[2][dd][cq] + Os[3][dd][cq];
            Oq[dd] = (f16)(ov * inv);
        }
    }
}

// ---- Kernel 3: out projection. Block 64m x 64n, Wo^T staged in LDS. -------
__global__ __launch_bounds__(256) void out_gemm(
    const f16* __restrict__ Ob, const float* __restrict__ Wo,
    const float* __restrict__ bo, float* __restrict__ out)
{
    __shared__ f16 Wl[64 * WLS];
    const int t = threadIdx.x, w = t >> 6, lane = t & 63;
    const int l15 = lane & 15, quad = lane >> 4;
    const int m0 = blockIdx.x * 64 + w * 16;
    const int n0 = blockIdx.y * 64;

    {
        const int nl = t & 63, kb = t >> 6;
        for (int kk = 0; kk < 64; ++kk) {
            const int k = kk * 4 + kb;
            Wl[nl * WLS + k] = (f16)Wo[(size_t)k * DIN + n0 + nl];
        }
    }
    __syncthreads();

    const int rA = m0 + l15, bA = rA >> 11, qA = rA & (Ln - 1);

    f4 acc[4] = {{0.f,0.f,0.f,0.f},{0.f,0.f,0.f,0.f},{0.f,0.f,0.f,0.f},{0.f,0.f,0.f,0.f}};
    for (int k0 = 0; k0 < DIN; k0 += 32) {
        const int h = k0 >> 5;                    // frag stays inside one head
        h8 af = *(const h8*)(Ob + (((size_t)(bA * Hn + h)) * Ln + qA) * DEPTH + quad * 8);
        #pragma unroll
        for (int tt = 0; tt < 4; ++tt) {
            h8 bf = *(const h8*)(Wl + (tt * 16 + l15) * WLS + k0 + quad * 8);
            acc[tt] = __builtin_amdgcn_mfma_f32_16x16x32_f16(af, bf, acc[tt], 0, 0, 0);
        }
    }
    #pragma unroll
    for (int tt = 0; tt < 4; ++tt) {
        const int c = n0 + tt * 16 + l15;
        const float bb = bo[c];
        #pragma unroll
        for (int r = 0; r < 4; ++r)
            out[(size_t)(m0 + quad * 4 + r) * DIN + c] = acc[tt][r] + bb;
    }
}

// ===========================================================================
// FALLBACK PATH (proven R4): fused kernel, zero workspace
// ===========================================================================
#define QT 128
#define KT 32
#define TS 34
#define SST (KT + 1)

__global__ __launch_bounds__(512) void fb_fused_attn(
    const float* __restrict__ Xq, const float* __restrict__ Xk,
    const float* __restrict__ Xv, const int* __restrict__ mask,
    const float* __restrict__ Wq, const float* __restrict__ bq,
    const float* __restrict__ Wk, const float* __restrict__ bk,
    const float* __restrict__ Wv, const float* __restrict__ bv,
    float* __restrict__ out)
{
    __shared__ float Qs[QT * TS];
    __shared__ float Ks[KT * TS];
    __shared__ float Vs[KT * TS];
    __shared__ float Ss[QT * SST];
    __shared__ float mrow[QT], lrow[QT], arow[QT];
    __shared__ int mk[KT];

    const int t = threadIdx.x;
    const int d = t & 31;
    const int rg = t >> 5;
    const int q0 = blockIdx.x * QT;
    const int h = blockIdx.y;
    const int b = blockIdx.z;
    const int hc = h * DEPTH + d;

    {
        const float bqv = bq[hc];
        for (int i = 0; i < 8; ++i) {
            const int r = rg + 16 * i;
            const float* x = Xq + ((size_t)(b * Ln + q0 + r)) * DIN;
            float acc = bqv;
            #pragma unroll 8
            for (int k = 0; k < DIN; ++k) acc = fmaf(x[k], Wq[k * DIN + hc], acc);
            Qs[r * TS + d] = acc * SCALE;
        }
    }
    if (t < QT) { mrow[t] = -INFINITY; lrow[t] = 0.f; }
    float o_acc[8];
    #pragma unroll
    for (int i = 0; i < 8; ++i) o_acc[i] = 0.f;

    const float bkv = bk[hc], bvv = bv[hc];

    for (int kt = 0; kt < Ln / KT; ++kt) {
        const int k0 = kt * KT;
        #pragma unroll
        for (int i = 0; i < 2; ++i) {
            const int r = rg + 16 * i;
            const float* xk = Xk + ((size_t)(b * Ln + k0 + r)) * DIN;
            const float* xv = Xv + ((size_t)(b * Ln + k0 + r)) * DIN;
            float aK = bkv, aV = bvv;
            #pragma unroll 4
            for (int k = 0; k < DIN; ++k) {
                aK = fmaf(xk[k], Wk[k * DIN + hc], aK);
                aV = fmaf(xv[k], Wv[k * DIN + hc], aV);
            }
            Ks[r * TS + d] = aK;
            Vs[r * TS + d] = aV;
        }
        if (t < KT) mk[t] = mask[b * Ln + k0 + t];
        __syncthreads();

        for (int idx = t; idx < QT * KT; idx += 512) {
            const int r = idx >> 5, k = idx & (KT - 1);
            const float2* qv = (const float2*)(Qs + r * TS);
            const float2* kv = (const float2*)(Ks + k * TS);
            float s = 0.f;
            #pragma unroll
            for (int j = 0; j < 16; ++j) {
                float2 a = qv[j], c = kv[j];
                s += a.x * c.x + a.y * c.y;
            }
            Ss[r * SST + k] = mk[k] ? s : NEGC;
        }
        __syncthreads();

        if (t < QT) {
            float tm = -INFINITY;
            #pragma unroll 8
            for (int k = 0; k < KT; ++k) tm = fmaxf(tm, Ss[t * SST + k]);
            const float nm = fmaxf(mrow[t], tm);
            arow[t] = __expf(mrow[t] - nm);
            mrow[t] = nm;
        }
        __syncthreads();

        for (int idx = t; idx < QT * KT; idx += 512) {
            const int r = idx >> 5, k = idx & (KT - 1);
            Ss[r * SST + k] = __expf(Ss[r * SST + k] - mrow[r]);
        }
        __syncthreads();

        if (t < QT) {
            float rs = 0.f;
            #pragma unroll 8
            for (int k = 0; k < KT; ++k) rs += Ss[t * SST + k];
            lrow[t] = arow[t] * lrow[t] + rs;
        }
        #pragma unroll
        for (int i = 0; i < 8; ++i) {
            const int r = rg + 16 * i;
            const float a = arow[r];
            float acc = o_acc[i] * a;
            const float* pr = Ss + r * SST;
            const float* vc = Vs + d;
            #pragma unroll 8
            for (int k = 0; k < KT; ++k) acc = fmaf(pr[k], vc[k * TS], acc);
            o_acc[i] = acc;
        }
        __syncthreads();
    }
    #pragma unroll
    for (int i = 0; i < 8; ++i) {
        const int r = rg + 16 * i;
        out[((size_t)(b * Ln + q0 + r)) * DIN + hc] = o_acc[i] / lrow[r];
    }
}

__global__ __launch_bounds__(256) void fb_out_proj(
    const float* __restrict__ Wo, const float* __restrict__ bo,
    float* __restrict__ out)
{
    __shared__ float xr[4][DIN];
    const int col = threadIdx.x;
    const int r0 = blockIdx.x * 4;
    #pragma unroll
    for (int rr = 0; rr < 4; ++rr)
        xr[rr][col] = out[(size_t)(r0 + rr) * DIN + col];
    __syncthreads();
    const float bb = bo[col];
    float a0 = bb, a1 = bb, a2 = bb, a3 = bb;
    #pragma unroll 4
    for (int k = 0; k < DIN; ++k) {
        const float w = Wo[k * DIN + col];
        a0 = fmaf(xr[0][k], w, a0);
        a1 = fmaf(xr[1][k], w, a1);
        a2 = fmaf(xr[2][k], w, a2);
        a3 = fmaf(xr[3][k], w, a3);
    }
    float* o = out + (size_t)r0 * DIN + col;
    o[0] = a0; o[DIN] = a1; o[2 * DIN] = a2; o[3 * DIN] = a3;
}

// ===========================================================================
extern "C" void kernel_launch(void* const* d_in, const int* in_sizes, int n_in,
                              void* d_out, int out_size, void* d_ws, size_t ws_size,
                              hipStream_t stream) {
    const float* Xq = (const float*)d_in[0];
    const float* Xk = (const float*)d_in[1];
    const float* Xv = (const float*)d_in[2];
    const int* mask = (const int*)d_in[3];
    const float* Wq = (const float*)d_in[4];
    const float* bq = (const float*)d_in[5];
    const float* Wk = (const float*)d_in[6];
    const float* bk = (const float*)d_in[7];
    const float* Wv = (const float*)d_in[8];
    const float* bv = (const float*)d_in[9];
    const float* Wo = (const float*)d_in[10];
    const float* bo = (const float*)d_in[11];
    float* out = (float*)d_out;

    const size_t HB_E = (size_t)Bn * Hn * Ln * DEPTH;     // 1M f16 each
    const size_t need = 3 * HB_E * sizeof(f16);           // 6 MB

    if (ws_size >= need) {
        f16* Qb = (f16*)d_ws;    // becomes O after flash_mfma
        f16* Kb = Qb + HB_E;
        f16* Vt = Kb + HB_E;
        proj_gemm<<<dim3(Bn * Ln / 128, DIN / 64, 3), 256, 0, stream>>>(
            Xq, Xk, Xv, Wq, Wk, Wv, bq, bk, bv, Qb, Kb, Vt);
        flash_mfma<<<dim3(Bn * Hn, Ln / 32), 256, 0, stream>>>(Qb, Kb, Vt, mask, Qb);
        out_gemm<<<dim3(Bn * Ln / 64, DIN / 64), 256, 0, stream>>>(Qb, Wo, bo, out);
    } else {
        fb_fused_attn<<<dim3(Ln / QT, Hn, Bn), 512, 0, stream>>>(
            Xq, Xk, Xv, mask, Wq, bq, Wk, bk, Wv, bv, out);
        fb_out_proj<<<Bn * Ln / 4, 256, 0, stream>>>(Wo, bo, out);
    }
}

// Round 12
// 126.375 us; speedup vs baseline: 1.1463x; 1.1463x over previous
//
#include <hip/hip_runtime.h>

#define Bn 2
#define Ln 2048
#define DIN 256
#define Hn 8
#define DEPTH 32
#define SCALE 0.17677669529663687f      // 1/sqrt(32)
#define NEGC (-4294967296.0f)           // float32(-2^32+1)

typedef _Float16 f16;
typedef _Float16 h8 __attribute__((ext_vector_type(8)));   // K=32 A/B frag: 4 VGPR
typedef _Float16 h4 __attribute__((ext_vector_type(4)));   // K=16 A/B frag: 2 VGPR
typedef float f4 __attribute__((ext_vector_type(4)));      // C/D frag: 4 f32

#define WLS 264   // LDS W^T row stride (f16): 528B, 16B-aligned frags

// ===========================================================================
// MFMA pipeline. Fragment layouts (verified m89/m91/m120 + R11 pass):
//   K=32: A[m=lane&15][k=quad*8+j]  B[n=lane&15][k=quad*8+j]
//   K=16: A[m=lane&15][k=quad*4+j]  B[n=lane&15][k=quad*4+j]
//   D[row m = quad*4+reg][col n = lane&15]   (both shapes)
// flash: S^T = K.Q^T (K=32), mask bias in C-init; exp'd S^T C-regs are
// directly the K=16 PV B-frags. 64 q-rows/wave amortizes the scattered
// K/V line traffic 4x (R11 post-mortem: TA/L1 line-throughput bound).
// ===========================================================================

// ---- Kernel 1: QKV projection GEMM. Block: 128m x 64n, W^T staged in LDS.
// Q (pre-scaled) / K head-major [b,h,L,32]; V TRANSPOSED [b,h,32,L].
__global__ __launch_bounds__(256) void proj_gemm(
    const float* __restrict__ Xq, const float* __restrict__ Xk, const float* __restrict__ Xv,
    const float* __restrict__ Wq, const float* __restrict__ Wk, const float* __restrict__ Wv,
    const float* __restrict__ bq, const float* __restrict__ bk, const float* __restrict__ bv,
    f16* __restrict__ Qb, f16* __restrict__ Kb, f16* __restrict__ Vt)
{
    __shared__ f16 Wl[64 * WLS];   // 33 KB: W^T tile [n_local][k]
    const int p = blockIdx.z;
    const float* X = p == 0 ? Xq : p == 1 ? Xk : Xv;
    const float* W = p == 0 ? Wq : p == 1 ? Wk : Wv;
    const float* bias = p == 0 ? bq : p == 1 ? bk : bv;

    const int t = threadIdx.x, w = t >> 6, lane = t & 63;
    const int l15 = lane & 15, quad = lane >> 4;
    const int n0 = blockIdx.y * 64;

    {   // stage W[k][n0+nl] -> Wl[nl][k] (f16); coalesced 256B global rows
        const int nl = t & 63, kb = t >> 6;
        for (int kk = 0; kk < 64; ++kk) {
            const int k = kk * 4 + kb;
            Wl[nl * WLS + k] = (f16)W[(size_t)k * DIN + n0 + nl];
        }
    }
    __syncthreads();

    const int m0w = blockIdx.x * 128 + w * 32;
    const float* A0 = X + (size_t)(m0w + l15) * DIN;
    const float* A1 = X + (size_t)(m0w + 16 + l15) * DIN;

    f4 acc[2][4];
    #pragma unroll
    for (int mi = 0; mi < 2; ++mi)
        #pragma unroll
        for (int tt = 0; tt < 4; ++tt) acc[mi][tt] = (f4){0.f, 0.f, 0.f, 0.f};

    for (int k0 = 0; k0 < DIN; k0 += 32) {
        float4 xa0 = *(const float4*)(A0 + k0 + quad * 8);
        float4 xb0 = *(const float4*)(A0 + k0 + quad * 8 + 4);
        float4 xa1 = *(const float4*)(A1 + k0 + quad * 8);
        float4 xb1 = *(const float4*)(A1 + k0 + quad * 8 + 4);
        h8 af0 = { (f16)xa0.x, (f16)xa0.y, (f16)xa0.z, (f16)xa0.w,
                   (f16)xb0.x, (f16)xb0.y, (f16)xb0.z, (f16)xb0.w };
        h8 af1 = { (f16)xa1.x, (f16)xa1.y, (f16)xa1.z, (f16)xa1.w,
                   (f16)xb1.x, (f16)xb1.y, (f16)xb1.z, (f16)xb1.w };
        #pragma unroll
        for (int tt = 0; tt < 4; ++tt) {
            h8 bf = *(const h8*)(Wl + (tt * 16 + l15) * WLS + k0 + quad * 8);
            acc[0][tt] = __builtin_amdgcn_mfma_f32_16x16x32_f16(af0, bf, acc[0][tt], 0, 0, 0);
            acc[1][tt] = __builtin_amdgcn_mfma_f32_16x16x32_f16(af1, bf, acc[1][tt], 0, 0, 0);
        }
    }
    #pragma unroll
    for (int mi = 0; mi < 2; ++mi)
        #pragma unroll
        for (int tt = 0; tt < 4; ++tt) {
            const int c = n0 + tt * 16 + l15;        // 16-tile never straddles a head
            const float bb = bias[c];
            const int h = c >> 5, dd = c & 31;
            #pragma unroll
            for (int r = 0; r < 4; ++r) {
                const int row = m0w + mi * 16 + quad * 4 + r;
                const int b = row >> 11, l = row & (Ln - 1);
                const float v = acc[mi][tt][r] + bb;
                if (p == 0)
                    Qb[(((size_t)(b * Hn + h)) * Ln + l) * DEPTH + dd] = (f16)(v * SCALE);
                else if (p == 1)
                    Kb[(((size_t)(b * Hn + h)) * Ln + l) * DEPTH + dd] = (f16)v;
                else
                    Vt[(((size_t)(b * Hn + h)) * DEPTH + dd) * Ln + l] = (f16)v;
            }
        }
}

// ---- Kernel 2: split-K MFMA flash, 64 q-rows/wave, LDS-free main loop. ----
// Grid (hb=16, 32): block = 64 q-rows; wave w = keys [w*512,(w+1)*512).
// Per 64-key tile: 16 S-MFMA (K=32) + 32 PV-MFMA (K=16); loads serve 4 q-frags.
__global__ __launch_bounds__(256) void flash_mfma(
    const f16* __restrict__ Qb, const f16* __restrict__ Kb,
    const f16* __restrict__ Vt, const int* __restrict__ mask,
    f16* __restrict__ Ob)
{
    __shared__ float Os[4][32][68];    // 34816 B, partial O^T [w][d][q]
    __shared__ float lS[4][64];
    const int t = threadIdx.x, w = t >> 6, lane = t & 63;
    const int l15 = lane & 15, quad = lane >> 4;
    const int hb = blockIdx.x;                 // h=hb&7, b=hb>>3; all qb of hb on 1 XCD
    const int q0 = blockIdx.y * 64;
    const int b = hb >> 3;
    const f16* Qh = Qb + (size_t)hb * Ln * DEPTH;
    const f16* Kh = Kb + (size_t)hb * Ln * DEPTH;
    const f16* Vh = Vt + (size_t)hb * DEPTH * Ln;
    const int* mrow = mask + b * Ln;
    const int k_base = w * (Ln / 4);

    h8 qf[4];                                   // B-frags: q = q0 + qg*16 + l15
    #pragma unroll
    for (int qg = 0; qg < 4; ++qg)
        qf[qg] = *(const h8*)(Qh + (size_t)(q0 + qg * 16 + l15) * DEPTH + quad * 8);

    f4 o[2][4];                                 // [d-group][q-group]
    #pragma unroll
    for (int i = 0; i < 2; ++i)
        #pragma unroll
        for (int j = 0; j < 4; ++j) o[i][j] = (f4){0.f, 0.f, 0.f, 0.f};
    float l_run[4] = {0.f, 0.f, 0.f, 0.f};      // per-lane q = q0 + qg*16 + l15

    for (int kt = 0; kt < Ln / 4 / 64; ++kt) {
        const int k0 = k_base + kt * 64;
        #pragma unroll
        for (int tt = 0; tt < 4; ++tt) {
            // one kf + one mask + two va loads serve all 4 q-frags
            h8 kf = *(const h8*)(Kh + (size_t)(k0 + tt * 16 + l15) * DEPTH + quad * 8);
            const int4 mk = *(const int4*)(mrow + k0 + tt * 16 + quad * 4);
            f4 bias4 = { mk.x ? 0.f : NEGC, mk.y ? 0.f : NEGC,
                         mk.z ? 0.f : NEGC, mk.w ? 0.f : NEGC };
            h4 va0 = *(const h4*)(Vh + (size_t)l15 * Ln        + k0 + tt * 16 + quad * 4);
            h4 va1 = *(const h4*)(Vh + (size_t)(16 + l15) * Ln + k0 + tt * 16 + quad * 4);
            f4 s[4];
            #pragma unroll
            for (int qg = 0; qg < 4; ++qg)
                s[qg] = __builtin_amdgcn_mfma_f32_16x16x32_f16(kf, qf[qg], bias4, 0, 0, 0);
            #pragma unroll
            for (int qg = 0; qg < 4; ++qg) {
                h4 pf;
                #pragma unroll
                for (int r = 0; r < 4; ++r) {
                    const float pv = __expf(s[qg][r]);
                    l_run[qg] += pv;
                    pf[r] = (f16)pv;
                }
                o[0][qg] = __builtin_amdgcn_mfma_f32_16x16x16f16(va0, pf, o[0][qg], 0, 0, 0);
                o[1][qg] = __builtin_amdgcn_mfma_f32_16x16x16f16(va1, pf, o[1][qg], 0, 0, 0);
            }
        }
    }
    // ---- wave partials ----
    #pragma unroll
    for (int qg = 0; qg < 4; ++qg) {
        l_run[qg] += __shfl_xor(l_run[qg], 16, 64);
        l_run[qg] += __shfl_xor(l_run[qg], 32, 64);
        if (quad == 0) lS[w][qg * 16 + l15] = l_run[qg];
        #pragma unroll
        for (int dg = 0; dg < 2; ++dg)
            #pragma unroll
            for (int r = 0; r < 4; ++r)
                Os[w][dg * 16 + quad * 4 + r][qg * 16 + l15] = o[dg][qg][r];
    }
    __syncthreads();

    // ---- combine 4 chunks: thread -> (q = t&63, d = (t>>6)*8 + i), h8 store ----
    {
        const int cq = t & 63, dv = t >> 6;
        const float ls = lS[0][cq] + lS[1][cq] + lS[2][cq] + lS[3][cq];
        const float inv = 1.0f / ls;
        h8 pack;
        #pragma unroll
        for (int i = 0; i < 8; ++i) {
            const int dd = dv * 8 + i;
            const float ov = Os[0][dd][cq] + Os[1][dd][cq] +
                             Os[2][dd][cq] + Os[3][dd][cq];
            pack[i] = (f16)(ov * inv);
        }
        *(h8*)(Ob + ((size_t)hb * Ln + q0 + cq) * DEPTH + dv * 8) = pack;
    }
}

// ---- Kernel 3: out projection. Block 64m x 64n, Wo^T staged in LDS. -------
__global__ __launch_bounds__(256) void out_gemm(
    const f16* __restrict__ Ob, const float* __restrict__ Wo,
    const float* __restrict__ bo, float* __restrict__ out)
{
    __shared__ f16 Wl[64 * WLS];
    const int t = threadIdx.x, w = t >> 6, lane = t & 63;
    const int l15 = lane & 15, quad = lane >> 4;
    const int m0 = blockIdx.x * 64 + w * 16;
    const int n0 = blockIdx.y * 64;

    {
        const int nl = t & 63, kb = t >> 6;
        for (int kk = 0; kk < 64; ++kk) {
            const int k = kk * 4 + kb;
            Wl[nl * WLS + k] = (f16)Wo[(size_t)k * DIN + n0 + nl];
        }
    }
    __syncthreads();

    const int rA = m0 + l15, bA = rA >> 11, qA = rA & (Ln - 1);

    f4 acc[4] = {{0.f,0.f,0.f,0.f},{0.f,0.f,0.f,0.f},{0.f,0.f,0.f,0.f},{0.f,0.f,0.f,0.f}};
    for (int k0 = 0; k0 < DIN; k0 += 32) {
        const int h = k0 >> 5;                    // frag stays inside one head
        h8 af = *(const h8*)(Ob + (((size_t)(bA * Hn + h)) * Ln + qA) * DEPTH + quad * 8);
        #pragma unroll
        for (int tt = 0; tt < 4; ++tt) {
            h8 bf = *(const h8*)(Wl + (tt * 16 + l15) * WLS + k0 + quad * 8);
            acc[tt] = __builtin_amdgcn_mfma_f32_16x16x32_f16(af, bf, acc[tt], 0, 0, 0);
        }
    }
    #pragma unroll
    for (int tt = 0; tt < 4; ++tt) {
        const int c = n0 + tt * 16 + l15;
        const float bb = bo[c];
        #pragma unroll
        for (int r = 0; r < 4; ++r)
            out[(size_t)(m0 + quad * 4 + r) * DIN + c] = acc[tt][r] + bb;
    }
}

// ===========================================================================
// FALLBACK PATH (proven R4): fused kernel, zero workspace
// ===========================================================================
#define QT 128
#define KT 32
#define TS 34
#define SST (KT + 1)

__global__ __launch_bounds__(512) void fb_fused_attn(
    const float* __restrict__ Xq, const float* __restrict__ Xk,
    const float* __restrict__ Xv, const int* __restrict__ mask,
    const float* __restrict__ Wq, const float* __restrict__ bq,
    const float* __restrict__ Wk, const float* __restrict__ bk,
    const float* __restrict__ Wv, const float* __restrict__ bv,
    float* __restrict__ out)
{
    __shared__ float Qs[QT * TS];
    __shared__ float Ks[KT * TS];
    __shared__ float Vs[KT * TS];
    __shared__ float Ss[QT * SST];
    __shared__ float mrow[QT], lrow[QT], arow[QT];
    __shared__ int mk[KT];

    const int t = threadIdx.x;
    const int d = t & 31;
    const int rg = t >> 5;
    const int q0 = blockIdx.x * QT;
    const int h = blockIdx.y;
    const int b = blockIdx.z;
    const int hc = h * DEPTH + d;

    {
        const float bqv = bq[hc];
        for (int i = 0; i < 8; ++i) {
            const int r = rg + 16 * i;
            const float* x = Xq + ((size_t)(b * Ln + q0 + r)) * DIN;
            float acc = bqv;
            #pragma unroll 8
            for (int k = 0; k < DIN; ++k) acc = fmaf(x[k], Wq[k * DIN + hc], acc);
            Qs[r * TS + d] = acc * SCALE;
        }
    }
    if (t < QT) { mrow[t] = -INFINITY; lrow[t] = 0.f; }
    float o_acc[8];
    #pragma unroll
    for (int i = 0; i < 8; ++i) o_acc[i] = 0.f;

    const float bkv = bk[hc], bvv = bv[hc];

    for (int kt = 0; kt < Ln / KT; ++kt) {
        const int k0 = kt * KT;
        #pragma unroll
        for (int i = 0; i < 2; ++i) {
            const int r = rg + 16 * i;
            const float* xk = Xk + ((size_t)(b * Ln + k0 + r)) * DIN;
            const float* xv = Xv + ((size_t)(b * Ln + k0 + r)) * DIN;
            float aK = bkv, aV = bvv;
            #pragma unroll 4
            for (int k = 0; k < DIN; ++k) {
                aK = fmaf(xk[k], Wk[k * DIN + hc], aK);
                aV = fmaf(xv[k], Wv[k * DIN + hc], aV);
            }
            Ks[r * TS + d] = aK;
            Vs[r * TS + d] = aV;
        }
        if (t < KT) mk[t] = mask[b * Ln + k0 + t];
        __syncthreads();

        for (int idx = t; idx < QT * KT; idx += 512) {
            const int r = idx >> 5, k = idx & (KT - 1);
            const float2* qv = (const float2*)(Qs + r * TS);
            const float2* kv = (const float2*)(Ks + k * TS);
            float s = 0.f;
            #pragma unroll
            for (int j = 0; j < 16; ++j) {
                float2 a = qv[j], c = kv[j];
                s += a.x * c.x + a.y * c.y;
            }
            Ss[r * SST + k] = mk[k] ? s : NEGC;
        }
        __syncthreads();

        if (t < QT) {
            float tm = -INFINITY;
            #pragma unroll 8
            for (int k = 0; k < KT; ++k) tm = fmaxf(tm, Ss[t * SST + k]);
            const float nm = fmaxf(mrow[t], tm);
            arow[t] = __expf(mrow[t] - nm);
            mrow[t] = nm;
        }
        __syncthreads();

        for (int idx = t; idx < QT * KT; idx += 512) {
            const int r = idx >> 5, k = idx & (KT - 1);
            Ss[r * SST + k] = __expf(Ss[r * SST + k] - mrow[r]);
        }
        __syncthreads();

        if (t < QT) {
            float rs = 0.f;
            #pragma unroll 8
            for (int k = 0; k < KT; ++k) rs += Ss[t * SST + k];
            lrow[t] = arow[t] * lrow[t] + rs;
        }
        #pragma unroll
        for (int i = 0; i < 8; ++i) {
            const int r = rg + 16 * i;
            const float a = arow[r];
            float acc = o_acc[i] * a;
            const float* pr = Ss + r * SST;
            const float* vc = Vs + d;
            #pragma unroll 8
            for (int k = 0; k < KT; ++k) acc = fmaf(pr[k], vc[k * TS], acc);
            o_acc[i] = acc;
        }
        __syncthreads();
    }
    #pragma unroll
    for (int i = 0; i < 8; ++i) {
        const int r = rg + 16 * i;
        out[((size_t)(b * Ln + q0 + r)) * DIN + hc] = o_acc[i] / lrow[r];
    }
}

__global__ __launch_bounds__(256) void fb_out_proj(
    const float* __restrict__ Wo, const float* __restrict__ bo,
    float* __restrict__ out)
{
    __shared__ float xr[4][DIN];
    const int col = threadIdx.x;
    const int r0 = blockIdx.x * 4;
    #pragma unroll
    for (int rr = 0; rr < 4; ++rr)
        xr[rr][col] = out[(size_t)(r0 + rr) * DIN + col];
    __syncthreads();
    const float bb = bo[col];
    float a0 = bb, a1 = bb, a2 = bb, a3 = bb;
    #pragma unroll 4
    for (int k = 0; k < DIN; ++k) {
        const float w = Wo[k * DIN + col];
        a0 = fmaf(xr[0][k], w, a0);
        a1 = fmaf(xr[1][k], w, a1);
        a2 = fmaf(xr[2][k], w, a2);
        a3 = fmaf(xr[3][k], w, a3);
    }
    float* o = out + (size_t)r0 * DIN + col;
    o[0] = a0; o[DIN] = a1; o[2 * DIN] = a2; o[3 * DIN] = a3;
}

// ===========================================================================
extern "C" void kernel_launch(void* const* d_in, const int* in_sizes, int n_in,
                              void* d_out, int out_size, void* d_ws, size_t ws_size,
                              hipStream_t stream) {
    const float* Xq = (const float*)d_in[0];
    const float* Xk = (const float*)d_in[1];
    const float* Xv = (const float*)d_in[2];
    const int* mask = (const int*)d_in[3];
    const float* Wq = (const float*)d_in[4];
    const float* bq = (const float*)d_in[5];
    const float* Wk = (const float*)d_in[6];
    const float* bk = (const float*)d_in[7];
    const float* Wv = (const float*)d_in[8];
    const float* bv = (const float*)d_in[9];
    const float* Wo = (const float*)d_in[10];
    const float* bo = (const float*)d_in[11];
    float* out = (float*)d_out;

    const size_t HB_E = (size_t)Bn * Hn * Ln * DEPTH;     // 1M f16 each
    const size_t need = 3 * HB_E * sizeof(f16);           // 6 MB

    if (ws_size >= need) {
        f16* Qb = (f16*)d_ws;    // becomes O after flash_mfma
        f16* Kb = Qb + HB_E;
        f16* Vt = Kb + HB_E;
        proj_gemm<<<dim3(Bn * Ln / 128, DIN / 64, 3), 256, 0, stream>>>(
            Xq, Xk, Xv, Wq, Wk, Wv, bq, bk, bv, Qb, Kb, Vt);
        flash_mfma<<<dim3(Bn * Hn, Ln / 64), 256, 0, stream>>>(Qb, Kb, Vt, mask, Qb);
        out_gemm<<<dim3(Bn * Ln / 64, DIN / 64), 256, 0, stream>>>(Qb, Wo, bo, out);
    } else {
        fb_fused_attn<<<dim3(Ln / QT, Hn, Bn), 512, 0, stream>>>(
            Xq, Xk, Xv, mask, Wq, bq, Wk, bk, Wv, bv, out);
        fb_out_proj<<<Bn * Ln / 4, 256, 0, stream>>>(Wo, bo, out);
    }
}

// Round 14
// 123.870 us; speedup vs baseline: 1.1695x; 1.0202x over previous
//
#include <hip/hip_runtime.h>

#define Bn 2
#define Ln 2048
#define DIN 256
#define Hn 8
#define DEPTH 32
#define SCALE 0.17677669529663687f      // 1/sqrt(32)
#define NEGC (-4294967296.0f)           // float32(-2^32+1)

typedef _Float16 f16;
typedef _Float16 h8 __attribute__((ext_vector_type(8)));   // K=32 A/B frag: 4 VGPR
typedef _Float16 h4 __attribute__((ext_vector_type(4)));   // K=16 A/B frag: 2 VGPR
typedef float f4 __attribute__((ext_vector_type(4)));      // C/D frag: 4 f32

#define WLS 264   // LDS W^T row stride (f16): 528B, 16B-aligned frags
#define NG  (Ln / 16)   // 128 16-row groups per (b,h)

// ===========================================================================
// MFMA pipeline with FRAGMENT-SWIZZLED intermediates:
//   K=32 A/B frag: [outer = lane&15][k = quad*8+j]
//   K=16 A   frag: [outer = lane&15][k = quad*4+j]
//   D: [row = quad*4+reg][col = lane&15]
// Qz/Kz: chunk per (hb, 16-row group g) = 512 f16: lane(quad*16+l15) holds
//   8 f16 = row (g*16+l15), depth (quad*8..+7) -> wave load 1024B contiguous.
// Vz: per (hb,g): TWO half-chunks of 256 f16 (d-halves); lane holds 4 f16 =
//   V[key=g*16+quad*4+j][d=dhalf*16+l15] -> wave load 512B contiguous.
//   Per-group footprint = 512 f16; per-hb = NG*512.  (R13 bug: reader used
//   NG*1024 stride — fixed here.)
// Oz: chunk per (row-group gm, h) = 512 f16: lane holds O[row=gm*16+l15]
//   [d=quad*8..+7].
// ===========================================================================

// ---- Kernel 1: QKV projection GEMM. Block: 128m x 64n, W^T staged in LDS.
__global__ __launch_bounds__(256) void proj_gemm(
    const float* __restrict__ Xq, const float* __restrict__ Xk, const float* __restrict__ Xv,
    const float* __restrict__ Wq, const float* __restrict__ Wk, const float* __restrict__ Wv,
    const float* __restrict__ bq, const float* __restrict__ bk, const float* __restrict__ bv,
    f16* __restrict__ Qz, f16* __restrict__ Kz, f16* __restrict__ Vz)
{
    __shared__ f16 Wl[64 * WLS];   // 33 KB: W^T tile [n_local][k]
    const int p = blockIdx.z;
    const float* X = p == 0 ? Xq : p == 1 ? Xk : Xv;
    const float* W = p == 0 ? Wq : p == 1 ? Wk : Wv;
    const float* bias = p == 0 ? bq : p == 1 ? bk : bv;

    const int t = threadIdx.x, w = t >> 6, lane = t & 63;
    const int l15 = lane & 15, quad = lane >> 4;
    const int n0 = blockIdx.y * 64;

    {   // stage W[k][n0+nl] -> Wl[nl][k] (f16); coalesced 256B global rows
        const int nl = t & 63, kb = t >> 6;
        for (int kk = 0; kk < 64; ++kk) {
            const int k = kk * 4 + kb;
            Wl[nl * WLS + k] = (f16)W[(size_t)k * DIN + n0 + nl];
        }
    }
    __syncthreads();

    const int m0w = blockIdx.x * 128 + w * 32;
    const float* A0 = X + (size_t)(m0w + l15) * DIN;
    const float* A1 = X + (size_t)(m0w + 16 + l15) * DIN;

    f4 acc[2][4];
    #pragma unroll
    for (int mi = 0; mi < 2; ++mi)
        #pragma unroll
        for (int tt = 0; tt < 4; ++tt) acc[mi][tt] = (f4){0.f, 0.f, 0.f, 0.f};

    for (int k0 = 0; k0 < DIN; k0 += 32) {
        float4 xa0 = *(const float4*)(A0 + k0 + quad * 8);
        float4 xb0 = *(const float4*)(A0 + k0 + quad * 8 + 4);
        float4 xa1 = *(const float4*)(A1 + k0 + quad * 8);
        float4 xb1 = *(const float4*)(A1 + k0 + quad * 8 + 4);
        h8 af0 = { (f16)xa0.x, (f16)xa0.y, (f16)xa0.z, (f16)xa0.w,
                   (f16)xb0.x, (f16)xb0.y, (f16)xb0.z, (f16)xb0.w };
        h8 af1 = { (f16)xa1.x, (f16)xa1.y, (f16)xa1.z, (f16)xa1.w,
                   (f16)xb1.x, (f16)xb1.y, (f16)xb1.z, (f16)xb1.w };
        #pragma unroll
        for (int tt = 0; tt < 4; ++tt) {
            h8 bf = *(const h8*)(Wl + (tt * 16 + l15) * WLS + k0 + quad * 8);
            acc[0][tt] = __builtin_amdgcn_mfma_f32_16x16x32_f16(af0, bf, acc[0][tt], 0, 0, 0);
            acc[1][tt] = __builtin_amdgcn_mfma_f32_16x16x32_f16(af1, bf, acc[1][tt], 0, 0, 0);
        }
    }
    #pragma unroll
    for (int mi = 0; mi < 2; ++mi)
        #pragma unroll
        for (int tt = 0; tt < 4; ++tt) {
            const int c = n0 + tt * 16 + l15;        // 16-tile never straddles a head
            const float bb = bias[c];
            const int h = c >> 5, dd = c & 31;
            #pragma unroll
            for (int r = 0; r < 4; ++r) {
                const int row = m0w + mi * 16 + quad * 4 + r;
                const int b = row >> 11, l = row & (Ln - 1);
                const float v = acc[mi][tt][r] + bb;
                const size_t hbg = (size_t)(b * Hn + h) * NG + (l >> 4);
                if (p == 0)        // Q swizzled (K=32 B-frag chunks), pre-scaled
                    Qz[(hbg * 64 + (dd >> 3) * 16 + (l & 15)) * 8 + (dd & 7)] =
                        (f16)(v * SCALE);
                else if (p == 1)   // K swizzled (K=32 A-frag chunks)
                    Kz[(hbg * 64 + (dd >> 3) * 16 + (l & 15)) * 8 + (dd & 7)] = (f16)v;
                else               // V swizzled (K=16 A-frag chunks, 2 d-halves)
                    Vz[((hbg * 2 + (dd >> 4)) * 64 + ((l & 15) >> 2) * 16 + (dd & 15)) * 4
                       + (l & 3)] = (f16)v;
            }
        }
}

// ---- Kernel 2: split-K MFMA flash, swizzled coalesced loads. --------------
// Grid (hb=16, 32): block = 64 q-rows; wave w = keys [w*512,(w+1)*512).
__global__ __launch_bounds__(256) void flash_mfma(
    const f16* __restrict__ Qz, const f16* __restrict__ Kz,
    const f16* __restrict__ Vz, const int* __restrict__ mask,
    f16* __restrict__ Oz)
{
    __shared__ float Os[4][32][68];    // 34816 B, partial O^T [w][d][q]
    __shared__ float lS[4][64];
    const int t = threadIdx.x, w = t >> 6, lane = t & 63;
    const int l15 = lane & 15, quad = lane >> 4;
    const int hb = blockIdx.x;                 // h=hb&7, b=hb>>3
    const int q0 = blockIdx.y * 64;
    const int b = hb >> 3, h = hb & 7;
    const f16* Qh = Qz + (size_t)hb * NG * 512;      // 512 f16 per group chunk
    const f16* Kh = Kz + (size_t)hb * NG * 512;
    const f16* Vh = Vz + (size_t)hb * NG * 512;      // 2 half-chunks of 256 f16/group
    const int* mrow = mask + b * Ln;
    const int k_base = w * (Ln / 4);

    h8 qf[4];                                   // coalesced 1024B chunk loads
    #pragma unroll
    for (int qg = 0; qg < 4; ++qg)
        qf[qg] = *(const h8*)(Qh + ((size_t)(q0 / 16 + qg) * 64 + lane) * 8);

    f4 o[2][4];                                 // [d-group][q-group]
    #pragma unroll
    for (int i = 0; i < 2; ++i)
        #pragma unroll
        for (int j = 0; j < 4; ++j) o[i][j] = (f4){0.f, 0.f, 0.f, 0.f};
    float l_run[4] = {0.f, 0.f, 0.f, 0.f};      // per-lane q = q0 + qg*16 + l15

    for (int kt = 0; kt < Ln / 4 / 64; ++kt) {
        const int k0 = k_base + kt * 64;
        #pragma unroll
        for (int tt = 0; tt < 4; ++tt) {
            const int g = (k0 >> 4) + tt;
            // coalesced: kf 1024B, va 512B each, mask 64B
            h8 kf = *(const h8*)(Kh + ((size_t)g * 64 + lane) * 8);
            const int4 mk = *(const int4*)(mrow + g * 16 + quad * 4);
            f4 bias4 = { mk.x ? 0.f : NEGC, mk.y ? 0.f : NEGC,
                         mk.z ? 0.f : NEGC, mk.w ? 0.f : NEGC };
            h4 va0 = *(const h4*)(Vh + ((size_t)(g * 2)     * 64 + lane) * 4);
            h4 va1 = *(const h4*)(Vh + ((size_t)(g * 2 + 1) * 64 + lane) * 4);
            f4 s[4];
            #pragma unroll
            for (int qg = 0; qg < 4; ++qg)
                s[qg] = __builtin_amdgcn_mfma_f32_16x16x32_f16(kf, qf[qg], bias4, 0, 0, 0);
            #pragma unroll
            for (int qg = 0; qg < 4; ++qg) {
                h4 pf;
                #pragma unroll
                for (int r = 0; r < 4; ++r) {
                    const float pv = __expf(s[qg][r]);
                    l_run[qg] += pv;
                    pf[r] = (f16)pv;
                }
                o[0][qg] = __builtin_amdgcn_mfma_f32_16x16x16f16(va0, pf, o[0][qg], 0, 0, 0);
                o[1][qg] = __builtin_amdgcn_mfma_f32_16x16x16f16(va1, pf, o[1][qg], 0, 0, 0);
            }
        }
    }
    // ---- wave partials ----
    #pragma unroll
    for (int qg = 0; qg < 4; ++qg) {
        l_run[qg] += __shfl_xor(l_run[qg], 16, 64);
        l_run[qg] += __shfl_xor(l_run[qg], 32, 64);
        if (quad == 0) lS[w][qg * 16 + l15] = l_run[qg];
        #pragma unroll
        for (int dg = 0; dg < 2; ++dg)
            #pragma unroll
            for (int r = 0; r < 4; ++r)
                Os[w][dg * 16 + quad * 4 + r][qg * 16 + l15] = o[dg][qg][r];
    }
    __syncthreads();

    // ---- combine 4 chunks -> Oz chunk (gm = global row>>4, h) ----
    {
        const int cq = t & 63, dv = t >> 6;      // dv = depth quad 0..3
        const float ls = lS[0][cq] + lS[1][cq] + lS[2][cq] + lS[3][cq];
        const float inv = 1.0f / ls;
        h8 pack;
        #pragma unroll
        for (int i = 0; i < 8; ++i) {
            const int dd = dv * 8 + i;
            const float ov = Os[0][dd][cq] + Os[1][dd][cq] +
                             Os[2][dd][cq] + Os[3][dd][cq];
            pack[i] = (f16)(ov * inv);
        }
        const int gm = b * NG + ((q0 + cq) >> 4);      // global-row group
        *(h8*)(Oz + (((size_t)gm * 8 + h) * 64 + dv * 16 + (cq & 15)) * 8) = pack;
    }
}

// ---- Kernel 3: out projection; A-frags coalesced from Oz. -----------------
__global__ __launch_bounds__(256) void out_gemm(
    const f16* __restrict__ Oz, const float* __restrict__ Wo,
    const float* __restrict__ bo, float* __restrict__ out)
{
    __shared__ f16 Wl[64 * WLS];
    const int t = threadIdx.x, w = t >> 6, lane = t & 63;
    const int l15 = lane & 15, quad = lane >> 4;
    const int m0 = blockIdx.x * 64 + w * 16;
    const int n0 = blockIdx.y * 64;

    {
        const int nl = t & 63, kb = t >> 6;
        for (int kk = 0; kk < 64; ++kk) {
            const int k = kk * 4 + kb;
            Wl[nl * WLS + k] = (f16)Wo[(size_t)k * DIN + n0 + nl];
        }
    }
    __syncthreads();

    const int gm = m0 >> 4;

    f4 acc[4] = {{0.f,0.f,0.f,0.f},{0.f,0.f,0.f,0.f},{0.f,0.f,0.f,0.f},{0.f,0.f,0.f,0.f}};
    for (int k0 = 0; k0 < DIN; k0 += 32) {
        const int h = k0 >> 5;
        h8 af = *(const h8*)(Oz + (((size_t)gm * 8 + h) * 64 + lane) * 8);  // 1024B coalesced
        #pragma unroll
        for (int tt = 0; tt < 4; ++tt) {
            h8 bf = *(const h8*)(Wl + (tt * 16 + l15) * WLS + k0 + quad * 8);
            acc[tt] = __builtin_amdgcn_mfma_f32_16x16x32_f16(af, bf, acc[tt], 0, 0, 0);
        }
    }
    #pragma unroll
    for (int tt = 0; tt < 4; ++tt) {
        const int c = n0 + tt * 16 + l15;
        const float bb = bo[c];
        #pragma unroll
        for (int r = 0; r < 4; ++r)
            out[(size_t)(m0 + quad * 4 + r) * DIN + c] = acc[tt][r] + bb;
    }
}

// ===========================================================================
// FALLBACK PATH (proven R4): fused kernel, zero workspace
// ===========================================================================
#define QT 128
#define KT 32
#define TS 34
#define SST (KT + 1)

__global__ __launch_bounds__(512) void fb_fused_attn(
    const float* __restrict__ Xq, const float* __restrict__ Xk,
    const float* __restrict__ Xv, const int* __restrict__ mask,
    const float* __restrict__ Wq, const float* __restrict__ bq,
    const float* __restrict__ Wk, const float* __restrict__ bk,
    const float* __restrict__ Wv, const float* __restrict__ bv,
    float* __restrict__ out)
{
    __shared__ float Qs[QT * TS];
    __shared__ float Ks[KT * TS];
    __shared__ float Vs[KT * TS];
    __shared__ float Ss[QT * SST];
    __shared__ float mrow[QT], lrow[QT], arow[QT];
    __shared__ int mk[KT];

    const int t = threadIdx.x;
    const int d = t & 31;
    const int rg = t >> 5;
    const int q0 = blockIdx.x * QT;
    const int h = blockIdx.y;
    const int b = blockIdx.z;
    const int hc = h * DEPTH + d;

    {
        const float bqv = bq[hc];
        for (int i = 0; i < 8; ++i) {
            const int r = rg + 16 * i;
            const float* x = Xq + ((size_t)(b * Ln + q0 + r)) * DIN;
            float acc = bqv;
            #pragma unroll 8
            for (int k = 0; k < DIN; ++k) acc = fmaf(x[k], Wq[k * DIN + hc], acc);
            Qs[r * TS + d] = acc * SCALE;
        }
    }
    if (t < QT) { mrow[t] = -INFINITY; lrow[t] = 0.f; }
    float o_acc[8];
    #pragma unroll
    for (int i = 0; i < 8; ++i) o_acc[i] = 0.f;

    const float bkv = bk[hc], bvv = bv[hc];

    for (int kt = 0; kt < Ln / KT; ++kt) {
        const int k0 = kt * KT;
        #pragma unroll
        for (int i = 0; i < 2; ++i) {
            const int r = rg + 16 * i;
            const float* xk = Xk + ((size_t)(b * Ln + k0 + r)) * DIN;
            const float* xv = Xv + ((size_t)(b * Ln + k0 + r)) * DIN;
            float aK = bkv, aV = bvv;
            #pragma unroll 4
            for (int k = 0; k < DIN; ++k) {
                aK = fmaf(xk[k], Wk[k * DIN + hc], aK);
                aV = fmaf(xv[k], Wv[k * DIN + hc], aV);
            }
            Ks[r * TS + d] = aK;
            Vs[r * TS + d] = aV;
        }
        if (t < KT) mk[t] = mask[b * Ln + k0 + t];
        __syncthreads();

        for (int idx = t; idx < QT * KT; idx += 512) {
            const int r = idx >> 5, k = idx & (KT - 1);
            const float2* qv = (const float2*)(Qs + r * TS);
            const float2* kv = (const float2*)(Ks + k * TS);
            float s = 0.f;
            #pragma unroll
            for (int j = 0; j < 16; ++j) {
                float2 a = qv[j], c = kv[j];
                s += a.x * c.x + a.y * c.y;
            }
            Ss[r * SST + k] = mk[k] ? s : NEGC;
        }
        __syncthreads();

        if (t < QT) {
            float tm = -INFINITY;
            #pragma unroll 8
            for (int k = 0; k < KT; ++k) tm = fmaxf(tm, Ss[t * SST + k]);
            const float nm = fmaxf(mrow[t], tm);
            arow[t] = __expf(mrow[t] - nm);
            mrow[t] = nm;
        }
        __syncthreads();

        for (int idx = t; idx < QT * KT; idx += 512) {
            const int r = idx >> 5, k = idx & (KT - 1);
            Ss[r * SST + k] = __expf(Ss[r * SST + k] - mrow[r]);
        }
        __syncthreads();

        if (t < QT) {
            float rs = 0.f;
            #pragma unroll 8
            for (int k = 0; k < KT; ++k) rs += Ss[t * SST + k];
            lrow[t] = arow[t] * lrow[t] + rs;
        }
        #pragma unroll
        for (int i = 0; i < 8; ++i) {
            const int r = rg + 16 * i;
            const float a = arow[r];
            float acc = o_acc[i] * a;
            const float* pr = Ss + r * SST;
            const float* vc = Vs + d;
            #pragma unroll 8
            for (int k = 0; k < KT; ++k) acc = fmaf(pr[k], vc[k * TS], acc);
            o_acc[i] = acc;
        }
        __syncthreads();
    }
    #pragma unroll
    for (int i = 0; i < 8; ++i) {
        const int r = rg + 16 * i;
        out[((size_t)(b * Ln + q0 + r)) * DIN + hc] = o_acc[i] / lrow[r];
    }
}

__global__ __launch_bounds__(256) void fb_out_proj(
    const float* __restrict__ Wo, const float* __restrict__ bo,
    float* __restrict__ out)
{
    __shared__ float xr[4][DIN];
    const int col = threadIdx.x;
    const int r0 = blockIdx.x * 4;
    #pragma unroll
    for (int rr = 0; rr < 4; ++rr)
        xr[rr][col] = out[(size_t)(r0 + rr) * DIN + col];
    __syncthreads();
    const float bb = bo[col];
    float a0 = bb, a1 = bb, a2 = bb, a3 = bb;
    #pragma unroll 4
    for (int k = 0; k < DIN; ++k) {
        const float w = Wo[k * DIN + col];
        a0 = fmaf(xr[0][k], w, a0);
        a1 = fmaf(xr[1][k], w, a1);
        a2 = fmaf(xr[2][k], w, a2);
        a3 = fmaf(xr[3][k], w, a3);
    }
    float* o = out + (size_t)r0 * DIN + col;
    o[0] = a0; o[DIN] = a1; o[2 * DIN] = a2; o[3 * DIN] = a3;
}

// ===========================================================================
extern "C" void kernel_launch(void* const* d_in, const int* in_sizes, int n_in,
                              void* d_out, int out_size, void* d_ws, size_t ws_size,
                              hipStream_t stream) {
    const float* Xq = (const float*)d_in[0];
    const float* Xk = (const float*)d_in[1];
    const float* Xv = (const float*)d_in[2];
    const int* mask = (const int*)d_in[3];
    const float* Wq = (const float*)d_in[4];
    const float* bq = (const float*)d_in[5];
    const float* Wk = (const float*)d_in[6];
    const float* bk = (const float*)d_in[7];
    const float* Wv = (const float*)d_in[8];
    const float* bv = (const float*)d_in[9];
    const float* Wo = (const float*)d_in[10];
    const float* bo = (const float*)d_in[11];
    float* out = (float*)d_out;

    const size_t HB_E = (size_t)Bn * Hn * Ln * DEPTH;     // 1M f16 each
    const size_t need = 4 * HB_E * sizeof(f16);           // 8 MB

    if (ws_size >= need) {
        f16* Qz = (f16*)d_ws;
        f16* Kz = Qz + HB_E;
        f16* Vz = Kz + HB_E;
        f16* Oz = Vz + HB_E;
        proj_gemm<<<dim3(Bn * Ln / 128, DIN / 64, 3), 256, 0, stream>>>(
            Xq, Xk, Xv, Wq, Wk, Wv, bq, bk, bv, Qz, Kz, Vz);
        flash_mfma<<<dim3(Bn * Hn, Ln / 64), 256, 0, stream>>>(Qz, Kz, Vz, mask, Oz);
        out_gemm<<<dim3(Bn * Ln / 64, DIN / 64), 256, 0, stream>>>(Oz, Wo, bo, out);
    } else {
        fb_fused_attn<<<dim3(Ln / QT, Hn, Bn), 512, 0, stream>>>(
            Xq, Xk, Xv, mask, Wq, bq, Wk, bk, Wv, bv, out);
        fb_out_proj<<<Bn * Ln / 4, 256, 0, stream>>>(Wo, bo, out);
    }
}